// Round 7
// baseline (6216.922 us; speedup 1.0000x reference)
//
#include <hip/hip_runtime.h>
#include <math.h>

#define B_  16
#define TE_ 400
#define TD_ 64
#define E_  256
#define H_  512
#define H2_ 1024
#define V_  32000

typedef __attribute__((ext_vector_type(4))) float f32x4;
typedef __attribute__((ext_vector_type(8))) short s16x8;
typedef __attribute__((ext_vector_type(8))) unsigned short u16x8;
typedef __attribute__((ext_vector_type(4))) unsigned short u16x4;

__device__ __forceinline__ float bf2f(unsigned short u){
  union { unsigned int i; float f; } v; v.i = ((unsigned int)u) << 16; return v.f;
}
__device__ __forceinline__ unsigned short f2bf(float f){
  union { float f; unsigned int i; } v; v.f = f;
  return (unsigned short)((v.i + 0x7fffu + ((v.i >> 16) & 1u)) >> 16);
}
__device__ __forceinline__ float sigmoidf_(float x){ return 1.f/(1.f + expf(-x)); }

__device__ __forceinline__ void gl_lds16(const void* gsrc, void* ldst){
  __builtin_amdgcn_global_load_lds(
      (const __attribute__((address_space(1))) unsigned int*)gsrc,
      (__attribute__((address_space(3))) unsigned int*)ldst, 16, 0, 0);
}
// issue one 4KB sub-block (4 x 1KB wave-level loads)
__device__ __forceinline__ void issue4(const char* gsrc, char* ldst, int l){
  #pragma unroll
  for (int q = 0; q < 4; ++q)
    gl_lds16(gsrc + q*1024 + (size_t)l*16, ldst + q*1024);
}

// barrier lines spread over 8 x 16KB pages (distinct L2 homes); inst*64B within page
__device__ __forceinline__ void d_arrive(unsigned* bars, int inst){
  __threadfence();
  __hip_atomic_fetch_add(bars + (blockIdx.x & 7u)*4096 + inst*16, 1u, __ATOMIC_RELAXED, __HIP_MEMORY_SCOPE_AGENT);
}
__device__ __forceinline__ void d_poll(unsigned* bars, int inst, unsigned tgt){
  int it = 0;
  for(;;){
    unsigned s = 0;
    #pragma unroll
    for (int k = 0; k < 8; ++k)
      s += __hip_atomic_load(bars + k*4096 + inst*16, __ATOMIC_RELAXED, __HIP_MEMORY_SCOPE_AGENT);
    if (s >= tgt) break;
    if (it < 6) __builtin_amdgcn_s_sleep(1);
    else if (it < 24) __builtin_amdgcn_s_sleep(4);
    else __builtin_amdgcn_s_sleep(16);
    ++it;
  }
  __threadfence();
}

// ---------------- init ----------------
__global__ void k_init(unsigned* bars, float* ctxn, float* psumT){
  int gid = blockIdx.x*256 + threadIdx.x;
  if (gid < 99328) bars[gid] = 0u;
  if (gid < 32768) ctxn[gid] = 0.f;
  if (gid < 32) psumT[gid] = 0.f;
}

// ---------------- embedding gather ----------------
__global__ void k_gather(const float* __restrict__ emb, const int* __restrict__ idx,
                         unsigned short* __restrict__ out, int T){
  int wv = threadIdx.x >> 6, l = threadIdx.x & 63;
  int row = blockIdx.x*4 + wv;
  if (row >= T*B_) return;
  int t = row >> 4, b = row & 15;
  int tok = idx[b*T + t];
  float4 v = *(const float4*)(emb + (size_t)tok*E_ + l*4);
  u16x4 o; o[0]=f2bf(v.x); o[1]=f2bf(v.y); o[2]=f2bf(v.z); o[3]=f2bf(v.w);
  *(u16x4*)(out + (size_t)row*E_ + l*4) = o;
}

// ---------------- prep encoder weights: gate-grouped [dir][2048][768] ----------------
__global__ void k_prep_enc(const float* __restrict__ Wih_f, const float* __restrict__ Whh_f,
                           const float* __restrict__ Wih_b, const float* __restrict__ Whh_b,
                           unsigned short* __restrict__ Wenc){
  int it = blockIdx.x*256 + threadIdx.x;
  int dir = it / (2048*96); int rem = it % (2048*96);
  int pr = rem / 96; int kc = rem % 96; int k0 = kc*8;
  int g = pr >> 6, r = pr & 63, gate = r >> 4, ul = r & 15;
  int orig = gate*H_ + g*16 + ul;
  const float* Wih = dir ? Wih_b : Wih_f;
  const float* Whh = dir ? Whh_b : Whh_f;
  u16x8 o;
  #pragma unroll
  for (int e = 0; e < 8; ++e){
    int k = k0 + e;
    float v = (k < E_) ? Wih[(size_t)orig*E_ + k] : Whh[(size_t)orig*H_ + (k - E_)];
    o[e] = f2bf(v);
  }
  *(u16x8*)(Wenc + ((size_t)dir*2048 + pr)*768 + k0) = o;
}

// ===== decoder stream preps: sub-block format [16 rows][128 K] = row*256B + ((k8*16)^((row&7)<<4)) =====
// SA[g][wv][24KB]: sb 0,1 = v (W_da rows g*16+row, K = wv*256+sb*128); sb 2..5 = gate wv K (sb-2)*128
__device__ __forceinline__ void prep_SA_item(int it, const float* __restrict__ Whh_d,
                                             const float* __restrict__ W_da, char* __restrict__ SA){
  int g = it / 6144; int r = it % 6144;
  int wv = r / 1536; int r2 = r % 1536;
  int sb = r2 >> 8; int e = r2 & 255;
  int row = e >> 4, k8 = e & 15;
  u16x8 o;
  if (sb < 2){
    int k = wv*256 + sb*128 + k8*8;
    #pragma unroll
    for (int e2 = 0; e2 < 8; ++e2)
      o[e2] = f2bf(W_da[(size_t)(g*16 + row)*H2_ + k + e2]);
  } else {
    int orig = wv*H2_ + g*16 + row;
    int k = (sb-2)*128 + k8*8;
    #pragma unroll
    for (int e2 = 0; e2 < 8; ++e2)
      o[e2] = f2bf(Whh_d[(size_t)orig*H2_ + k + e2]);
  }
  size_t off = (size_t)g*98304 + (size_t)wv*24576 + (size_t)sb*4096
             + (size_t)(row*256 + ((k8*16) ^ ((row&7)<<4)));
  *(u16x8*)(SA + off) = o;
}
// SB[g][wv][16KB]: gate wv, K = 512 + sb*128
__device__ __forceinline__ void prep_SB_item(int it, const float* __restrict__ Whh_d,
                                             char* __restrict__ SB){
  int g = it >> 12; int r = it & 4095;
  int wv = r >> 10; int sb = (r >> 8) & 3; int e = r & 255;
  int row = e >> 4, k8 = e & 15;
  int orig = wv*H2_ + g*16 + row;
  int k = 512 + sb*128 + k8*8;
  u16x8 o;
  #pragma unroll
  for (int e2 = 0; e2 < 8; ++e2)
    o[e2] = f2bf(Whh_d[(size_t)orig*H2_ + k + e2]);
  size_t off = (size_t)g*65536 + (size_t)wv*16384 + (size_t)sb*4096
             + (size_t)(row*256 + ((k8*16) ^ ((row&7)<<4)));
  *(u16x8*)(SB + off) = o;
}
// C{A,B}[g][wv][32KB]: gate wv, Wih_d col = colbase + sb*128
__device__ __forceinline__ void prep_C_item(int it, const float* __restrict__ Wih_d,
                                            char* __restrict__ C, int colbase){
  int g = it >> 13; int r = it & 8191;
  int wv = r >> 11; int sb = (r >> 8) & 7; int e = r & 255;
  int row = e >> 4, k8 = e & 15;
  int orig = wv*H2_ + g*16 + row;
  int col = colbase + sb*128 + k8*8;
  u16x8 o;
  #pragma unroll
  for (int e2 = 0; e2 < 8; ++e2)
    o[e2] = f2bf(Wih_d[(size_t)orig*2304 + col + e2]);
  size_t off = (size_t)g*131072 + (size_t)wv*32768 + (size_t)sb*4096
             + (size_t)(row*256 + ((k8*16) ^ ((row&7)<<4)));
  *(u16x8*)(C + off) = o;
}

// ---------------- prep WihEmbGrp [4096][256] ----------------
__global__ void k_prep_wihemb(const float* __restrict__ Wih_d, unsigned short* __restrict__ Wemb){
  int it = blockIdx.x*256 + threadIdx.x;
  int p = it >> 5; int k0 = (it & 31)*8;
  int g = p >> 6, gate = (p >> 4) & 3, ul = p & 15;
  int orig = gate*H2_ + g*16 + ul;
  u16x8 o;
  #pragma unroll
  for (int e = 0; e < 8; ++e)
    o[e] = f2bf(Wih_d[(size_t)orig*2304 + k0 + e]);
  *(u16x8*)(Wemb + (size_t)p*256 + k0) = o;
}

// ---------------- zinit GEMM: [1024][4096] f32 = decemb @ WihEmbGrp^T + b_d ----------------
__global__ void __launch_bounds__(256, 2) k_zinit(
    const unsigned short* __restrict__ A,
    const unsigned short* __restrict__ Bw,
    const float* __restrict__ bd,
    float* __restrict__ Cz)
{
  __shared__ unsigned short Ab[128*72];
  __shared__ unsigned short Bt[128*72];
  int p = blockIdx.x;
  int mt = p >> 5, nt = p & 31;
  int m0 = mt*128, n0 = nt*128;
  int tid = threadIdx.x, wvv = tid>>6, l = tid&63;
  int wr = wvv>>1, wc = wvv&1;
  f32x4 zero4 = {0.f,0.f,0.f,0.f};
  f32x4 acc[4][4];
  #pragma unroll
  for (int a=0;a<4;++a){
    #pragma unroll
    for (int b=0;b<4;++b) acc[a][b] = zero4;
  }
  for (int k0 = 0; k0 < 256; k0 += 64){
    #pragma unroll
    for (int qq = 0; qq < 4; ++qq){
      int idx8 = (tid + qq*256)*8;
      int r = idx8 >> 6, k = idx8 & 63;
      *(u16x8*)(Ab + r*72 + k) = *(const u16x8*)(A + (size_t)(m0+r)*256 + k0 + k);
      *(u16x8*)(Bt + r*72 + k) = *(const u16x8*)(Bw + (size_t)(n0+r)*256 + k0 + k);
    }
    __syncthreads();
    #pragma unroll
    for (int ks = 0; ks < 2; ++ks){
      s16x8 af[4], bf[4];
      #pragma unroll
      for (int fi=0;fi<4;++fi)
        af[fi] = *(const s16x8*)(Ab + (wr*64+fi*16+(l&15))*72 + ks*32 + (l>>4)*8);
      #pragma unroll
      for (int fj=0;fj<4;++fj)
        bf[fj] = *(const s16x8*)(Bt + (wc*64+fj*16+(l&15))*72 + ks*32 + (l>>4)*8);
      #pragma unroll
      for (int fi=0;fi<4;++fi){
        #pragma unroll
        for (int fj=0;fj<4;++fj)
          acc[fi][fj] = __builtin_amdgcn_mfma_f32_16x16x32_bf16(af[fi], bf[fj], acc[fi][fj], 0,0,0);
      }
    }
    __syncthreads();
  }
  #pragma unroll
  for (int fj=0;fj<4;++fj){
    int col = n0 + wc*64 + fj*16 + (l&15);
    int orig = ((col>>4)&3)*H2_ + (col>>6)*16 + (col&15);
    float bias = bd[orig];
    #pragma unroll
    for (int fi=0;fi<4;++fi){
      #pragma unroll
      for (int j=0;j<4;++j){
        int row = m0 + wr*64 + fi*16 + (l>>4)*4 + j;
        Cz[(size_t)row*4096 + col] = acc[fi][fj][j] + bias;
      }
    }
  }
}

// ---------------- zx GEMM: zx[dir][6400][2048] bf16 = xs @ WihGrp^T + b ----------------
__global__ void __launch_bounds__(256, 2) k_zx(
    const unsigned short* __restrict__ xs,
    const unsigned short* __restrict__ Wenc,
    const float* __restrict__ b_f, const float* __restrict__ b_b,
    unsigned short* __restrict__ zx)
{
  __shared__ unsigned short Ab[128*72];
  __shared__ unsigned short Bt[128*72];
  int pblk = blockIdx.x;
  int dir = pblk / 800; int rem = pblk % 800;
  int mt = rem >> 4, nt = rem & 15;
  int m0 = mt*128, n0 = nt*128;
  int tid = threadIdx.x, wvv = tid>>6, l = tid&63;
  int wr = wvv>>1, wc = wvv&1;
  f32x4 zero4 = {0.f,0.f,0.f,0.f};
  f32x4 acc[4][4];
  #pragma unroll
  for (int a=0;a<4;++a){
    #pragma unroll
    for (int b=0;b<4;++b) acc[a][b] = zero4;
  }
  for (int k0 = 0; k0 < 256; k0 += 64){
    #pragma unroll
    for (int qq = 0; qq < 4; ++qq){
      int idx8 = (tid + qq*256)*8;
      int r = idx8 >> 6, k = idx8 & 63;
      *(u16x8*)(Ab + r*72 + k) = *(const u16x8*)(xs + (size_t)(m0+r)*256 + k0 + k);
      *(u16x8*)(Bt + r*72 + k) = *(const u16x8*)(Wenc + ((size_t)dir*2048 + n0+r)*768 + k0 + k);
    }
    __syncthreads();
    #pragma unroll
    for (int ks = 0; ks < 2; ++ks){
      s16x8 af[4], bf[4];
      #pragma unroll
      for (int fi=0;fi<4;++fi)
        af[fi] = *(const s16x8*)(Ab + (wr*64+fi*16+(l&15))*72 + ks*32 + (l>>4)*8);
      #pragma unroll
      for (int fj=0;fj<4;++fj)
        bf[fj] = *(const s16x8*)(Bt + (wc*64+fj*16+(l&15))*72 + ks*32 + (l>>4)*8);
      #pragma unroll
      for (int fi=0;fi<4;++fi){
        #pragma unroll
        for (int fj=0;fj<4;++fj)
          acc[fi][fj] = __builtin_amdgcn_mfma_f32_16x16x32_bf16(af[fi], bf[fj], acc[fi][fj], 0,0,0);
      }
    }
    __syncthreads();
  }
  const float* bsrc = dir ? b_b : b_f;
  #pragma unroll
  for (int fj=0;fj<4;++fj){
    int col = n0 + wc*64 + fj*16 + (l&15);
    float bias = bsrc[((col>>4)&3)*512 + (col>>6)*16 + (col&15)];
    #pragma unroll
    for (int fi=0;fi<4;++fi){
      #pragma unroll
      for (int j=0;j<4;++j){
        int row = m0 + wr*64 + fi*16 + (l>>4)*4 + j;
        zx[((size_t)dir*6400 + row)*2048 + col] = f2bf(acc[fi][fj][j] + bias);
      }
    }
  }
}

// ---------------- Penc = enc_out @ W_ea^T (bf16) ----------------
__global__ void __launch_bounds__(256, 2) k_penc(
    const unsigned short* __restrict__ enc,
    const float* __restrict__ Wea,
    unsigned short* __restrict__ P)
{
  __shared__ unsigned short Ab[128*72];
  __shared__ unsigned short Bt[128*72];
  int p = blockIdx.x;
  int mt = p >> 3, nt = p & 7;
  int m0 = mt*128, n0 = nt*128;
  int tid = threadIdx.x, wvv = tid>>6, l = tid&63;
  int wr = wvv>>1, wc = wvv&1;
  f32x4 zero4 = {0.f,0.f,0.f,0.f};
  f32x4 acc[4][4];
  #pragma unroll
  for (int a=0;a<4;++a){
    #pragma unroll
    for (int b=0;b<4;++b) acc[a][b] = zero4;
  }
  for (int k0 = 0; k0 < 1024; k0 += 64){
    #pragma unroll
    for (int qq = 0; qq < 4; ++qq){
      int idx8 = (tid + qq*256)*8;
      int r = idx8 >> 6, k = idx8 & 63;
      *(u16x8*)(Ab + r*72 + k) = *(const u16x8*)(enc + (size_t)(m0+r)*1024 + k0 + k);
    }
    #pragma unroll
    for (int qq = 0; qq < 4; ++qq){
      int idx8 = (tid + qq*256)*8;
      int r = idx8 >> 6, k = idx8 & 63;
      const float* src = Wea + (size_t)(n0+r)*1024 + k0 + k;
      float4 v0 = *(const float4*)src;
      float4 v1 = *(const float4*)(src+4);
      u16x8 o;
      o[0]=f2bf(v0.x); o[1]=f2bf(v0.y); o[2]=f2bf(v0.z); o[3]=f2bf(v0.w);
      o[4]=f2bf(v1.x); o[5]=f2bf(v1.y); o[6]=f2bf(v1.z); o[7]=f2bf(v1.w);
      *(u16x8*)(Bt + r*72 + k) = o;
    }
    __syncthreads();
    #pragma unroll
    for (int ks = 0; ks < 2; ++ks){
      s16x8 af[4], bf[4];
      #pragma unroll
      for (int fi=0;fi<4;++fi)
        af[fi] = *(const s16x8*)(Ab + (wr*64+fi*16+(l&15))*72 + ks*32 + (l>>4)*8);
      #pragma unroll
      for (int fj=0;fj<4;++fj)
        bf[fj] = *(const s16x8*)(Bt + (wc*64+fj*16+(l&15))*72 + ks*32 + (l>>4)*8);
      #pragma unroll
      for (int fi=0;fi<4;++fi){
        #pragma unroll
        for (int fj=0;fj<4;++fj)
          acc[fi][fj] = __builtin_amdgcn_mfma_f32_16x16x32_bf16(af[fi], bf[fj], acc[fi][fj], 0,0,0);
      }
    }
    __syncthreads();
  }
  #pragma unroll
  for (int fj=0;fj<4;++fj){
    int col = n0 + wc*64 + fj*16 + (l&15);
    #pragma unroll
    for (int fi=0;fi<4;++fi){
      #pragma unroll
      for (int j=0;j<4;++j){
        int row = m0 + wr*64 + fi*16 + (l>>4)*4 + j;
        P[(size_t)row*1024 + col] = f2bf(acc[fi][fj][j]);
      }
    }
  }
}

// ---------------- persistent bi-LSTM encoder (K=512, zx-init) + prep WGs ----------------
__global__ void __launch_bounds__(256, 1) k_encoder(
    const unsigned short* __restrict__ zx,
    const unsigned short* __restrict__ Wenc,
    const float* __restrict__ h0, const float* __restrict__ c0,
    unsigned short* __restrict__ enc_out,
    unsigned short* __restrict__ hbuf,
    float* __restrict__ h0dec, float* __restrict__ c0dec,
    unsigned* __restrict__ bars,
    const float* __restrict__ Whh_d, const float* __restrict__ W_da,
    const float* __restrict__ Wih_d,
    char* __restrict__ SA, char* __restrict__ SB,
    char* __restrict__ CA, char* __restrict__ CB)
{
  extern __shared__ char smem[];
  int tid = threadIdx.x;
  int w = blockIdx.x;
  if (w >= 64){
    int base = (w - 64)*256 + tid;
    for (int it = base; it < 393216; it += 36864) prep_SA_item(it, Whh_d, W_da, SA);
    for (int it = base; it < 262144; it += 36864) prep_SB_item(it, Whh_d, SB);
    for (int it = base; it < 524288; it += 36864) prep_C_item(it, Wih_d, CA, 256);
    for (int it = base; it < 524288; it += 36864) prep_C_item(it, Wih_d, CB, 1280);
    return;
  }
  unsigned short* Wt = (unsigned short*)smem;            // [64][520]
  unsigned short* At = Wt + 64*520;                      // [16][520]
  float* zl = (float*)(At + 16*520);                     // [4][16][16]
  int dir = w >> 5, g = w & 31;
  int wv = tid >> 6, l = tid & 63;
  unsigned* ebars = bars + 32768;
  {
    const unsigned short* Wsrc = Wenc + ((size_t)dir*2048 + g*64)*768 + 256;
    int r = tid >> 2, s = tid & 3;
    for (int c = 0; c < 16; ++c)
      *(u16x8*)(Wt + r*520 + s*128 + c*8) = *(const u16x8*)(Wsrc + (size_t)r*768 + s*128 + c*8);
  }
  int bb = tid >> 4, ul = tid & 15;
  float creg = c0[((size_t)dir*16 + bb)*H_ + g*16 + ul];
  int kchunk = (l >> 4) * 8;
  f32x4 zero4 = { 0.f, 0.f, 0.f, 0.f };
  {
    int r = tid >> 4, s = tid & 15;
    for (int e = 0; e < 32; ++e)
      At[r*520 + s*32 + e] = f2bf(h0[((size_t)dir*16 + r)*H_ + s*32 + e]);
  }
  int tg0 = dir ? (TE_-1) : 0;
  const unsigned short* zrow = zx + ((size_t)dir*6400 + (size_t)tg0*16 + (l>>4)*4)*2048 + g*64 + wv*16 + (l&15);
  f32x4 a0cur;
  a0cur[0]=bf2f(zrow[0]); a0cur[1]=bf2f(zrow[2048]); a0cur[2]=bf2f(zrow[4096]); a0cur[3]=bf2f(zrow[6144]);
  __syncthreads();
  for (int t = 0; t < TE_; ++t){
    int tg = dir ? (TE_-1 - t) : t;
    f32x4 acc0 = a0cur, acc1 = zero4;
    const unsigned short* brow = Wt + (wv*16 + (l&15))*520 + kchunk;
    const unsigned short* ap   = At + (l&15)*520 + kchunk;
    #pragma unroll
    for (int ks = 0; ks < 16; ++ks){
      s16x8 afr = *(const s16x8*)(ap + ks*32);
      s16x8 bfr = *(const s16x8*)(brow + ks*32);
      if (ks & 1) acc1 = __builtin_amdgcn_mfma_f32_16x16x32_bf16(afr, bfr, acc1, 0, 0, 0);
      else        acc0 = __builtin_amdgcn_mfma_f32_16x16x32_bf16(afr, bfr, acc0, 0, 0, 0);
    }
    f32x4 acc = acc0 + acc1;
    #pragma unroll
    for (int j = 0; j < 4; ++j)
      zl[wv*256 + ((l>>4)*4 + j)*16 + (l&15)] = acc[j];
    __syncthreads();
    float zi = zl[0*256 + bb*16 + ul];
    float zf = zl[1*256 + bb*16 + ul];
    float zg = zl[2*256 + bb*16 + ul];
    float zo = zl[3*256 + bb*16 + ul];
    float iv = sigmoidf_(zi), fv = sigmoidf_(zf), gv = tanhf(zg), ov = sigmoidf_(zo);
    float cc = fv*creg + iv*gv;
    float hh = ov * tanhf(cc);
    creg = cc;
    int u = g*16 + ul;
    unsigned short hb = f2bf(hh);
    hbuf[((size_t)dir*2 + ((t+1)&1))*(16*H_) + bb*H_ + u] = hb;
    enc_out[((size_t)bb*TE_ + tg)*H2_ + dir*H_ + u] = hb;
    if (t == TE_-1){
      h0dec[(size_t)bb*H2_ + dir*H_ + u] = hh;
      c0dec[(size_t)bb*H2_ + dir*H_ + u] = cc;
    }
    int inst = dir*400 + t;
    __syncthreads();
    if (tid == 0){
      __threadfence();
      __hip_atomic_fetch_add(ebars + (g&3)*16384 + inst*16, 1u, __ATOMIC_RELAXED, __HIP_MEMORY_SCOPE_AGENT);
    }
    if (t+1 < TE_){
      int tg2 = dir ? (TE_-2 - t) : (t+1);
      const unsigned short* zr2 = zx + ((size_t)dir*6400 + (size_t)tg2*16 + (l>>4)*4)*2048 + g*64 + wv*16 + (l&15);
      a0cur[0]=bf2f(zr2[0]); a0cur[1]=bf2f(zr2[2048]); a0cur[2]=bf2f(zr2[4096]); a0cur[3]=bf2f(zr2[6144]);
    }
    if (tid == 0){
      int it = 0;
      for(;;){
        unsigned s_ = 0;
        #pragma unroll
        for (int k2 = 0; k2 < 4; ++k2)
          s_ += __hip_atomic_load(ebars + k2*16384 + inst*16, __ATOMIC_RELAXED, __HIP_MEMORY_SCOPE_AGENT);
        if (s_ >= 32) break;
        if (it < 6) __builtin_amdgcn_s_sleep(1);
        else __builtin_amdgcn_s_sleep(4);
        ++it;
      }
      __threadfence();
    }
    __syncthreads();
    if (t+1 < TE_){
      int r = tid >> 4, s = tid & 15;
      const unsigned short* hsrc = hbuf + ((size_t)dir*2 + ((t+1)&1))*(16*H_) + r*H_ + s*32;
      for (int c = 0; c < 4; ++c)
        *(u16x8*)(At + r*520 + s*32 + c*8) = *(const u16x8*)(hsrc + c*8);
    }
    __syncthreads();
  }
}

__global__ void k_dec_init(const float* __restrict__ h0dec, unsigned short* __restrict__ hreg){
  int gid = blockIdx.x*256 + threadIdx.x;
  if (gid < 16384) hreg[gid] = f2bf(h0dec[gid]);
}

// ---------------- persistent attention decoder (256 WGs: 64 A + 64 B + 128 attn) ----------------
__global__ void __launch_bounds__(256, 1) k_decoder(
  const char* __restrict__ SA, const char* __restrict__ SB,
  const char* __restrict__ CA, const char* __restrict__ CB,
  const float* __restrict__ zinit,
  const unsigned short* __restrict__ Penc,
  const unsigned short* __restrict__ enc_out,
  const float* __restrict__ c0dec,
  unsigned short* __restrict__ hreg,    // [2][16][1024] bf16
  unsigned short* __restrict__ xbuf,    // [16][1024] bf16 ctx_d
  float* __restrict__ ctxn,             // [2][16][1024]
  float* __restrict__ psumT,            // [2][16]
  unsigned short* __restrict__ vbuf,    // [64][16][1024] bf16
  unsigned short* __restrict__ bufh,    // [64][16][1024] bf16
  unsigned short* __restrict__ Av,      // [1024][3072]
  float* __restrict__ outHC,
  float* __restrict__ pz,               // [64][1024]
  unsigned* __restrict__ bars)
{
  extern __shared__ char smem[];
  int tid = threadIdx.x, w = blockIdx.x;
  int wv = tid >> 6, l = tid & 63;
  int bb = tid >> 4, ul = tid & 15;
  unsigned* flags = bars + 98304;

  if (w < 128){
    bool isA = (w < 64);
    int g = isA ? w : (w - 64);
    unsigned short* Ah = (unsigned short*)smem;          // [16][1032]
    char* myB = smem + 33024 + wv*16384;                 // 4 slots x 4KB per wave
    float* zlv = (float*)(smem + 98560);
    float* zlg = (float*)(smem + 102656);
    const char* myS1 = isA ? (SA + (size_t)g*98304 + (size_t)wv*24576)
                           : (SB + (size_t)g*65536 + (size_t)wv*16384);
    const char* myC  = isA ? (CA + (size_t)g*131072 + (size_t)wv*32768)
                           : (CB + (size_t)g*131072 + (size_t)wv*32768);
    int nsub1 = isA ? 6 : 4;
    int swz = ((l&7)<<4);
    float creg = 0.f;

    for (int i = 0; i < TD_; ++i){
      int p = i & 1;
      int iM = i*3, iAb = i*3+1, iBb = i*3+2;
      f32x4 z4 = {0.f,0.f,0.f,0.f};
      f32x4 accg = z4, accv = z4;
      if (isA){
        ctxn[(p^1)*16384 + g*256 + tid] = 0.f;
        if (g == 0 && tid < 16) psumT[(p^1)*16 + tid] = 0.f;
        const float* zsrc = zinit + ((size_t)i*16 + (l>>4)*4)*4096 + g*64 + wv*16 + (l&15);
        accg[0]=zsrc[0]; accg[1]=zsrc[4096]; accg[2]=zsrc[8192]; accg[3]=zsrc[12288];
      }
      // pre-issue phase-1 sub-blocks 0..3
      #pragma unroll
      for (int sb = 0; sb < 4; ++sb)
        issue4(myS1 + sb*4096, myB + sb*4096, l);
      // stage Ah = h
      { int r = tid >> 4, s2 = tid & 15;
        const unsigned short* hsrc = hreg + p*16384 + r*H2_ + s2*64;
        for (int c = 0; c < 8; ++c)
          *(u16x8*)(Ah + r*1032 + s2*64 + c*8) = *(const u16x8*)(hsrc + c*8);
      }
      __syncthreads();
      // ---- phase 1 ----
      for (int s = 0; s < nsub1; ++s){
        int rem = nsub1 - 1 - s;
        if (rem >= 3)      asm volatile("s_waitcnt vmcnt(12)" ::: "memory");
        else if (rem == 2) asm volatile("s_waitcnt vmcnt(8)" ::: "memory");
        else if (rem == 1) asm volatile("s_waitcnt vmcnt(4)" ::: "memory");
        else               asm volatile("s_waitcnt vmcnt(0)" ::: "memory");
        int Koff = isA ? ((s < 2) ? (wv*256 + s*128) : ((s-2)*128)) : (512 + s*128);
        const unsigned short* ap = Ah + (l&15)*1032 + Koff + (l>>4)*8;
        const char* Bz = myB + (s&3)*4096;
        if (isA && s < 2){
          #pragma unroll
          for (int ks = 0; ks < 4; ++ks){
            int k8 = ks*4 + (l>>4);
            s16x8 afr = *(const s16x8*)(ap + ks*32);
            s16x8 bfr = *(const s16x8*)(Bz + (l&15)*256 + ((k8*16) ^ swz));
            accv = __builtin_amdgcn_mfma_f32_16x16x32_bf16(afr, bfr, accv, 0,0,0);
          }
        } else {
          #pragma unroll
          for (int ks = 0; ks < 4; ++ks){
            int k8 = ks*4 + (l>>4);
            s16x8 afr = *(const s16x8*)(ap + ks*32);
            s16x8 bfr = *(const s16x8*)(Bz + (l&15)*256 + ((k8*16) ^ swz));
            accg = __builtin_amdgcn_mfma_f32_16x16x32_bf16(afr, bfr, accg, 0,0,0);
          }
        }
        __builtin_amdgcn_sched_barrier(0);
        if (s + 4 < nsub1) issue4(myS1 + (s+4)*4096, myB + ((s+4)&3)*4096, l);
      }
      // A: v cross-wave reduce + vbuf + barM arrival
      if (isA){
        #pragma unroll
        for (int j = 0; j < 4; ++j)
          zlv[wv*256 + ((l>>4)*4+j)*16 + (l&15)] = accv[j];
        __syncthreads();
        if (i > 0){
          float vv = zlv[bb*16+ul] + zlv[256+bb*16+ul] + zlv[512+bb*16+ul] + zlv[768+bb*16+ul];
          vbuf[((size_t)(i-1)*16 + bb)*H2_ + g*16 + ul] = f2bf(vv);
        }
        __syncthreads();
        if (tid == 0) d_arrive(bars, iM);
      }
      // pre-issue phase-2 weights (independent of ctx data)
      #pragma unroll
      for (int sb = 0; sb < 4; ++sb)
        issue4(myC + sb*4096, myB + sb*4096, l);
      if (tid == 0) d_poll(bars, iAb, 128);
      __syncthreads();
      // stage Atc (A: ctx_e normalized; B: ctx_d)
      if (isA){
        int r = tid >> 4, s2 = tid & 15;
        float inv = 1.f / psumT[p*16 + r];
        const float* cn = ctxn + p*16384 + (size_t)r*1024 + s2*64;
        for (int c8 = 0; c8 < 8; ++c8){
          float4 v0 = *(const float4*)(cn + c8*8);
          float4 v1 = *(const float4*)(cn + c8*8 + 4);
          u16x8 o;
          o[0]=f2bf(v0.x*inv); o[1]=f2bf(v0.y*inv); o[2]=f2bf(v0.z*inv); o[3]=f2bf(v0.w*inv);
          o[4]=f2bf(v1.x*inv); o[5]=f2bf(v1.y*inv); o[6]=f2bf(v1.z*inv); o[7]=f2bf(v1.w*inv);
          *(u16x8*)(Ah + r*1032 + s2*64 + c8*8) = o;
        }
        float val = ctxn[p*16384 + (size_t)bb*1024 + g*16 + ul] / psumT[p*16 + bb];
        Av[((size_t)bb*TD_ + i)*3072 + 1024 + g*16 + ul] = f2bf(val);
      } else {
        int r = tid >> 4, s2 = tid & 15;
        const unsigned short* xd = xbuf + (size_t)r*1024 + s2*64;
        for (int c8 = 0; c8 < 8; ++c8)
          *(u16x8*)(Ah + r*1032 + s2*64 + c8*8) = *(const u16x8*)(xd + c8*8);
      }
      __syncthreads();
      // ---- phase 2 ----
      for (int s = 0; s < 8; ++s){
        int rem = 7 - s;
        if (rem >= 3)      asm volatile("s_waitcnt vmcnt(12)" ::: "memory");
        else if (rem == 2) asm volatile("s_waitcnt vmcnt(8)" ::: "memory");
        else if (rem == 1) asm volatile("s_waitcnt vmcnt(4)" ::: "memory");
        else               asm volatile("s_waitcnt vmcnt(0)" ::: "memory");
        const unsigned short* ap = Ah + (l&15)*1032 + s*128 + (l>>4)*8;
        const char* Bz = myB + (s&3)*4096;
        #pragma unroll
        for (int ks = 0; ks < 4; ++ks){
          int k8 = ks*4 + (l>>4);
          s16x8 afr = *(const s16x8*)(ap + ks*32);
          s16x8 bfr = *(const s16x8*)(Bz + (l&15)*256 + ((k8*16) ^ swz));
          accg = __builtin_amdgcn_mfma_f32_16x16x32_bf16(afr, bfr, accg, 0,0,0);
        }
        __builtin_amdgcn_sched_barrier(0);
        if (s + 4 < 8) issue4(myC + (s+4)*4096, myB + ((s+4)&3)*4096, l);
      }
      #pragma unroll
      for (int j = 0; j < 4; ++j)
        zlg[wv*256 + ((l>>4)*4+j)*16 + (l&15)] = accg[j];
      __syncthreads();
      if (isA){
        if (tid == 0){
          int it = 0;
          while (__hip_atomic_load(flags + g*16, __ATOMIC_ACQUIRE, __HIP_MEMORY_SCOPE_AGENT) < (unsigned)(i+1)){
            if (it < 8) __builtin_amdgcn_s_sleep(1);
            else __builtin_amdgcn_s_sleep(4);
            ++it;
          }
          __threadfence();
        }
        __syncthreads();
        const float* pzg = pz + (size_t)g*1024;
        float zi = zlg[0*256 + bb*16 + ul] + pzg[0*256 + bb*16 + ul];
        float zf = zlg[1*256 + bb*16 + ul] + pzg[1*256 + bb*16 + ul];
        float zg_ = zlg[2*256 + bb*16 + ul] + pzg[2*256 + bb*16 + ul];
        float zo = zlg[3*256 + bb*16 + ul] + pzg[3*256 + bb*16 + ul];
        if (i == 0) creg = c0dec[(size_t)bb*H2_ + g*16 + ul];
        float iv = sigmoidf_(zi), fv = sigmoidf_(zf), gv = tanhf(zg_), ov = sigmoidf_(zo);
        float cc = fv*creg + iv*gv;
        float hh = ov*tanhf(cc);
        creg = cc;
        int u = g*16 + ul;
        unsigned short hb2 = f2bf(hh);
        hreg[((i+1)&1)*16384 + (size_t)bb*H2_ + u] = hb2;
        Av[((size_t)bb*TD_ + i)*3072 + u] = hb2;
        bufh[((size_t)i*16 + bb)*H2_ + u] = hb2;
        if (i == TD_-1){
          outHC[(size_t)bb*H2_ + u] = hh;
          outHC[16384 + (size_t)bb*H2_ + u] = cc;
        }
        __syncthreads();
        if (tid == 0) d_arrive(bars, iBb);
      } else {
        *(float4*)(pz + (size_t)g*1024 + tid*4) = *(const float4*)(zlg + tid*4);
        __syncthreads();
        if (tid == 0){
          __threadfence();
          __hip_atomic_store(flags + g*16, (unsigned)(i+1), __ATOMIC_RELEASE, __HIP_MEMORY_SCOPE_AGENT);
        }
      }
      if (tid == 0) d_poll(bars, iBb, 64);
      __syncthreads();
    }
  } else {
    // ---- attention WGs: 128 enc-attn, 16 of which (ec==0) also dec-attn ----
    int eb = (w-128) >> 3, ec = (w-128) & 7;
    bool isDec = (ec == 0);
    unsigned short* encL = (unsigned short*)smem;        // [50][1032]
    float* epL  = (float*)(smem + 103232);
    float* accL = (float*)(smem + 103488);
    float* dscL = (float*)(smem + 103744);
    for (int rr = 0; rr < 50; ++rr){
      const unsigned short* src = enc_out + ((size_t)eb*TE_ + ec*50 + rr)*H2_;
      *(u16x4*)(encL + rr*1032 + tid*4) = *(const u16x4*)(src + tid*4);
    }
    if (tid < 50) accL[tid] = 0.f;
    __syncthreads();
    for (int i = 0; i < TD_; ++i){
      int p = i & 1;
      int iM = i*3, iAb = i*3+1, iBb = i*3+2;
      const unsigned short* hb_ = hreg + p*16384 + eb*H2_ + l*16;
      u16x8 hv0 = *(const u16x8*)hb_;
      u16x8 hv1 = *(const u16x8*)(hb_ + 8);
      float hf[16];
      #pragma unroll
      for (int c = 0; c < 8; ++c){ hf[c] = bf2f(hv0[c]); hf[8+c] = bf2f(hv1[c]); }
      for (int rr = wv; rr < 50; rr += 4){
        const unsigned short* pr = Penc + ((size_t)(eb*TE_ + ec*50 + rr))*H2_ + l*16;
        u16x8 p0 = *(const u16x8*)pr;
        u16x8 p1 = *(const u16x8*)(pr + 8);
        float sc = 0.f;
        #pragma unroll
        for (int c = 0; c < 8; ++c) sc += hf[c]*bf2f(p0[c]);
        #pragma unroll
        for (int c = 0; c < 8; ++c) sc += hf[8+c]*bf2f(p1[c]);
        #pragma unroll
        for (int o = 1; o < 64; o <<= 1) sc += __shfl_xor(sc, o);
        if (l == 0){
          float es = expf(sc);
          float aold = accL[rr];
          float denom = (i == 0) ? 1.f : aold;
          accL[rr] = aold + es;
          epL[rr] = es / denom;
        }
      }
      __syncthreads();
      float tot = 0.f;
      for (int rr = 0; rr < 50; ++rr) tot += epL[rr];
      float a0=0.f,a1=0.f,a2=0.f,a3=0.f;
      for (int rr = 0; rr < 50; ++rr){
        float wgt = epL[rr];
        u16x4 ev = *(const u16x4*)(encL + rr*1032 + tid*4);
        a0 += wgt*bf2f(ev[0]); a1 += wgt*bf2f(ev[1]); a2 += wgt*bf2f(ev[2]); a3 += wgt*bf2f(ev[3]);
      }
      float* dst = ctxn + p*16384 + (size_t)eb*1024 + tid*4;
      atomicAdd(dst+0, a0); atomicAdd(dst+1, a1); atomicAdd(dst+2, a2); atomicAdd(dst+3, a3);
      if (tid == 0) atomicAdd(psumT + p*16 + eb, tot);
      __syncthreads();
      if (isDec){
        int db = eb;
        int col = tid*4;
        if (i == 0){
          u16x4 z4v = {0,0,0,0};
          *(u16x4*)(xbuf + (size_t)db*1024 + col) = z4v;
          *(u16x4*)(Av + ((size_t)db*TD_ + i)*3072 + 2048 + col) = z4v;
        } else {
          if (tid == 0) d_poll(bars, iM, 64);
          __syncthreads();
          const unsigned short* hq = hreg + p*16384 + db*H2_ + l*16;
          u16x8 h0v = *(const u16x8*)hq;
          u16x8 h1v = *(const u16x8*)(hq + 8);
          float qf[16];
          #pragma unroll
          for (int c = 0; c < 8; ++c){ qf[c] = bf2f(h0v[c]); qf[8+c] = bf2f(h1v[c]); }
          for (int tp = wv; tp < i; tp += 4){
            const unsigned short* vr = vbuf + ((size_t)tp*16 + db)*H2_ + l*16;
            u16x8 e0 = *(const u16x8*)vr;
            u16x8 e1 = *(const u16x8*)(vr + 8);
            float sc = 0.f;
            #pragma unroll
            for (int c = 0; c < 8; ++c) sc += qf[c]*bf2f(e0[c]);
            #pragma unroll
            for (int c = 0; c < 8; ++c) sc += qf[8+c]*bf2f(e1[c]);
            #pragma unroll
            for (int o = 1; o < 64; o <<= 1) sc += __shfl_xor(sc, o);
            if (l == 0) dscL[tp] = sc;
          }
          __syncthreads();
          float scv = (l < i) ? dscL[l] : -1e30f;
          float m = scv;
          #pragma unroll
          for (int o = 1; o < 64; o <<= 1) m = fmaxf(m, __shfl_xor(m, o));
          float e = (l < i) ? expf(scv - m) : 0.f;
          float ssum = e;
          #pragma unroll
          for (int o = 1; o < 64; o <<= 1) ssum += __shfl_xor(ssum, o);
          float wgt = e / ssum;
          float c0_=0.f,c1_=0.f,c2_=0.f,c3_=0.f;
          for (int tp = 0; tp < i; ++tp){
            float wt = __shfl(wgt, tp);
            u16x4 hv = *(const u16x4*)(bufh + ((size_t)tp*16 + db)*H2_ + col);
            c0_ += wt*bf2f(hv[0]); c1_ += wt*bf2f(hv[1]); c2_ += wt*bf2f(hv[2]); c3_ += wt*bf2f(hv[3]);
          }
          u16x4 o4; o4[0]=f2bf(c0_); o4[1]=f2bf(c1_); o4[2]=f2bf(c2_); o4[3]=f2bf(c3_);
          *(u16x4*)(xbuf + (size_t)db*1024 + col) = o4;
          *(u16x4*)(Av + ((size_t)db*TD_ + i)*3072 + 2048 + col) = o4;
        }
        __syncthreads();
      }
      if (tid == 0) d_arrive(bars, iAb);
      if (tid == 0) d_poll(bars, iBb, 64);
      __syncthreads();
    }
  }
}

// ---------------- vocab GEMM ----------------
__global__ void __launch_bounds__(256, 2) k_vocab_gemm(
    const unsigned short* __restrict__ Av,
    const float* __restrict__ Wv,
    const float* __restrict__ bv,
    float* __restrict__ out)
{
  __shared__ unsigned short Ab[128*72];
  __shared__ unsigned short Bt[128*72];
  int p = blockIdx.x;
  int mt = (p>>3)&7, nt = (p&7) + 8*(p>>6);
  if (nt >= 250) return;
  int m0 = mt*128, n0 = nt*128;
  int tid = threadIdx.x, wvv = tid>>6, l = tid&63;
  int wr = wvv>>1, wc = wvv&1;
  f32x4 zero4 = {0.f,0.f,0.f,0.f};
  f32x4 acc[4][4];
  #pragma unroll
  for (int a=0;a<4;++a){
    #pragma unroll
    for (int b=0;b<4;++b) acc[a][b] = zero4;
  }
  for (int k0 = 0; k0 < 3072; k0 += 64){
    #pragma unroll
    for (int qq = 0; qq < 4; ++qq){
      int idx8 = (tid + qq*256)*8;
      int r = idx8 >> 6, k = idx8 & 63;
      *(u16x8*)(Ab + r*72 + k) = *(const u16x8*)(Av + (size_t)(m0+r)*3072 + k0 + k);
    }
    #pragma unroll
    for (int qq = 0; qq < 4; ++qq){
      int idx8 = (tid + qq*256)*8;
      int r = idx8 >> 6, k = idx8 & 63;
      const float* src = Wv + (size_t)(n0+r)*3072 + k0 + k;
      float4 v0 = *(const float4*)src;
      float4 v1 = *(const float4*)(src+4);
      u16x8 o;
      o[0]=f2bf(v0.x); o[1]=f2bf(v0.y); o[2]=f2bf(v0.z); o[3]=f2bf(v0.w);
      o[4]=f2bf(v1.x); o[5]=f2bf(v1.y); o[6]=f2bf(v1.z); o[7]=f2bf(v1.w);
      *(u16x8*)(Bt + r*72 + k) = o;
    }
    __syncthreads();
    #pragma unroll
    for (int ks = 0; ks < 2; ++ks){
      s16x8 af[4], bf[4];
      #pragma unroll
      for (int fi=0;fi<4;++fi)
        af[fi] = *(const s16x8*)(Ab + (wr*64+fi*16+(l&15))*72 + ks*32 + (l>>4)*8);
      #pragma unroll
      for (int fj=0;fj<4;++fj)
        bf[fj] = *(const s16x8*)(Bt + (wc*64+fj*16+(l&15))*72 + ks*32 + (l>>4)*8);
      #pragma unroll
      for (int fi=0;fi<4;++fi){
        #pragma unroll
        for (int fj=0;fj<4;++fj)
          acc[fi][fj] = __builtin_amdgcn_mfma_f32_16x16x32_bf16(af[fi], bf[fj], acc[fi][fj], 0,0,0);
      }
    }
    __syncthreads();
  }
  #pragma unroll
  for (int fj=0;fj<4;++fj){
    int col = n0 + wc*64 + fj*16 + (l&15);
    float bias = bv[col];
    #pragma unroll
    for (int fi=0;fi<4;++fi){
      #pragma unroll
      for (int j=0;j<4;++j){
        int row = m0 + wr*64 + fi*16 + (l>>4)*4 + j;
        out[(size_t)row*V_ + col] = acc[fi][fj][j] + bias;
      }
    }
  }
}

// ---------------- in-place log-softmax ----------------
__global__ void k_logsoftmax(float* __restrict__ out){
  int row = blockIdx.x;
  float* x = out + (size_t)row*V_;
  int tid = threadIdx.x;
  __shared__ float red[64];
  float m = -1e30f;
  for (int c = tid; c < V_; c += 256) m = fmaxf(m, x[c]);
  #pragma unroll
  for (int o=1;o<64;o<<=1) m = fmaxf(m, __shfl_xor(m,o));
  if ((tid&63)==0) red[tid>>6] = m;
  __syncthreads();
  m = fmaxf(fmaxf(red[0],red[1]), fmaxf(red[2],red[3]));
  float s = 0.f;
  for (int c = tid; c < V_; c += 256) s += expf(x[c]-m);
  #pragma unroll
  for (int o=1;o<64;o<<=1) s += __shfl_xor(s,o);
  if ((tid&63)==0) red[8 + (tid>>6)] = s;
  __syncthreads();
  s = red[8]+red[9]+red[10]+red[11];
  float lse = m + logf(s);
  for (int c = tid; c < V_; c += 256) x[c] = x[c] - lse;
}

extern "C" void kernel_launch(void* const* d_in, const int* in_sizes, int n_in,
                              void* d_out, int out_size, void* d_ws, size_t ws_size,
                              hipStream_t stream){
  (void)in_sizes; (void)n_in; (void)out_size; (void)ws_size;
  const int*   enc_in = (const int*)d_in[0];
  const int*   dec_in = (const int*)d_in[1];
  const float* h0   = (const float*)d_in[4];
  const float* c0   = (const float*)d_in[5];
  const float* emb  = (const float*)d_in[6];
  const float* Wih_f= (const float*)d_in[7];
  const float* Whh_f= (const float*)d_in[8];
  const float* b_f  = (const float*)d_in[9];
  const float* Wih_b= (const float*)d_in[10];
  const float* Whh_b= (const float*)d_in[11];
  const float* b_b  = (const float*)d_in[12];
  const float* Wih_d= (const float*)d_in[13];
  const float* Whh_d= (const float*)d_in[14];
  const float* b_d  = (const float*)d_in[15];
  const float* W_ea = (const float*)d_in[16];
  const float* W_da = (const float*)d_in[17];
  const float* W_v  = (const float*)d_in[18];
  const float* b_v  = (const float*)d_in[19];
  float* out = (float*)d_out;
  char* ws = (char*)d_ws;

  size_t o_bars   = 0;                                  // 99328 u32 = 397312 B
  size_t o_ctxn   = 397312;
  size_t o_psumT  = o_ctxn + 131072;
  size_t o_pz     = o_psumT + 256;
  size_t o_xs     = o_pz + 262144;
  size_t o_decemb = o_xs + (size_t)6400*256*2;
  size_t o_Wenc   = o_decemb + (size_t)1024*256*2;
  size_t o_SA     = o_Wenc + (size_t)2*2048*768*2;
  size_t o_SB     = o_SA + (size_t)64*98304;
  size_t o_CA     = o_SB + (size_t)64*65536;
  size_t o_CB     = o_CA + (size_t)64*131072;
  size_t o_Wemb   = o_CB + (size_t)64*131072;
  size_t o_zinit  = o_Wemb + (size_t)4096*256*2;
  size_t o_zx     = o_zinit + (size_t)1024*4096*4;
  size_t o_enc    = o_zx + (size_t)2*6400*2048*2;
  size_t o_Penc   = o_enc + (size_t)16*400*1024*2;
  size_t o_hbuf   = o_Penc + (size_t)16*400*1024*2;
  size_t o_h0dec  = o_hbuf + (size_t)2*2*16*512*2;
  size_t o_c0dec  = o_h0dec + (size_t)16*1024*4;
  size_t o_hreg   = o_c0dec + (size_t)16*1024*4;
  size_t o_xbuf   = o_hreg + (size_t)2*16*1024*2;
  size_t o_vbuf   = o_xbuf + (size_t)16*1024*2;
  size_t o_bufh   = o_vbuf + (size_t)64*16*1024*2;
  size_t o_Av     = o_bufh + (size_t)64*16*1024*2;

  unsigned* bars        = (unsigned*)(ws + o_bars);
  float* ctxn           = (float*)(ws + o_ctxn);
  float* psumT          = (float*)(ws + o_psumT);
  float* pz             = (float*)(ws + o_pz);
  unsigned short* xs    = (unsigned short*)(ws + o_xs);
  unsigned short* decemb= (unsigned short*)(ws + o_decemb);
  unsigned short* Wenc  = (unsigned short*)(ws + o_Wenc);
  char* SA              = ws + o_SA;
  char* SB              = ws + o_SB;
  char* CA              = ws + o_CA;
  char* CB              = ws + o_CB;
  unsigned short* Wemb  = (unsigned short*)(ws + o_Wemb);
  float* zinit          = (float*)(ws + o_zinit);
  unsigned short* zx    = (unsigned short*)(ws + o_zx);
  unsigned short* encO  = (unsigned short*)(ws + o_enc);
  unsigned short* Penc  = (unsigned short*)(ws + o_Penc);
  unsigned short* hbuf  = (unsigned short*)(ws + o_hbuf);
  float* h0dec          = (float*)(ws + o_h0dec);
  float* c0dec          = (float*)(ws + o_c0dec);
  unsigned short* hreg  = (unsigned short*)(ws + o_hreg);
  unsigned short* xbuf  = (unsigned short*)(ws + o_xbuf);
  unsigned short* vbuf  = (unsigned short*)(ws + o_vbuf);
  unsigned short* bufh  = (unsigned short*)(ws + o_bufh);
  unsigned short* Av    = (unsigned short*)(ws + o_Av);

  hipFuncSetAttribute((const void*)k_encoder, hipFuncAttributeMaxDynamicSharedMemorySize, 90000);
  hipFuncSetAttribute((const void*)k_decoder, hipFuncAttributeMaxDynamicSharedMemorySize, 107520);

  k_init<<<392, 256, 0, stream>>>(bars, ctxn, psumT);
  k_gather<<<1600, 256, 0, stream>>>(emb, enc_in, xs, TE_);
  k_gather<<<256, 256, 0, stream>>>(emb, dec_in, decemb, TD_);
  k_prep_enc<<<1536, 256, 0, stream>>>(Wih_f, Whh_f, Wih_b, Whh_b, Wenc);
  k_prep_wihemb<<<512, 256, 0, stream>>>(Wih_d, Wemb);
  k_zinit<<<256, 256, 0, stream>>>(decemb, Wemb, b_d, zinit);
  k_zx<<<1600, 256, 0, stream>>>(xs, Wenc, b_f, b_b, zx);
  k_encoder<<<208, 256, 87296, stream>>>(zx, Wenc, h0, c0, encO, hbuf, h0dec, c0dec, bars,
                                         Whh_d, W_da, Wih_d, SA, SB, CA, CB);
  k_penc<<<400, 256, 0, stream>>>(encO, W_ea, Penc);
  k_dec_init<<<64, 256, 0, stream>>>(h0dec, hreg);
  k_decoder<<<256, 256, 107520, stream>>>(SA, SB, CA, CB, zinit, Penc, encO, c0dec,
                                          hreg, xbuf, ctxn, psumT, vbuf, bufh, Av,
                                          out + (size_t)32768000, pz, bars);
  k_vocab_gemm<<<2048, 256, 0, stream>>>(Av, W_v, b_v, out);
  k_logsoftmax<<<1024, 256, 0, stream>>>(out);
}